// Round 1
// 112.398 us; speedup vs baseline: 1.0474x; 1.0474x over previous
//
#include <hip/hip_runtime.h>

// Problem constants
#define BB   2
#define CIN  256
#define OC3  768
#define NG   4
#define GOC  64
#define C2   32
#define KK   49
#define PP   2304
#define HALF_P 1152

// Guarded Y2 layout: rows -3..50 (54), cols -3..52 at stride 56, 768 ch.
#define RS      56
#define BROWS   54
#define BSTRIDE (BROWS * RS * OC3)          // floats per batch = 2,322,432
#define IOFF    ((3 * RS + 3) * OC3)

// Workspace layout (bytes)
#define Y2_BYTES  (BB * BROWS * RS * OC3 * 4)
#define XT_OFF    Y2_BYTES
#define WT_OFF    (XT_OFF + BB * PP * 512 * 2)

typedef __attribute__((ext_vector_type(8))) short bf16x8;
typedef __attribute__((ext_vector_type(4))) float f32x4;

static __device__ __forceinline__ unsigned short f2bf_rne(float x) {
    unsigned int u = __float_as_uint(x);
    unsigned int r = u + 0x7FFFu + ((u >> 16) & 1u);
    return (unsigned short)(r >> 16);
}
static __device__ __forceinline__ float bf2f(unsigned short h) {
    return __uint_as_float(((unsigned int)h) << 16);
}

// ---------------------------------------------------------------------------
// DPP-based exact xor-lane exchange (VALU pipe; replaces ds_swizzle/bpermute
// on the CU-shared LDS pipe). Bit-identical permutation semantics.
//   xor1 = quad_perm{1,0,3,2} = 0xB1
//   xor2 = quad_perm{2,3,0,1} = 0x4E
//   xor8 = row_ror:8 (0x128)  (rotate by 8 within a 16-row == xor 8)
//   xor4 = xor1 ∘ xor2 ∘ xor7(row_half_mirror 0x141), since 1^2^7 = 4
//   xor16/xor32 stay on the LDS path (no single gfx9 DPP ctrl).
// ---------------------------------------------------------------------------
template <int C>
static __device__ __forceinline__ float dppf(float x) {
    return __int_as_float(__builtin_amdgcn_update_dpp(
        0, __float_as_int(x), C, 0xF, 0xF, true));
}
template <int D>
static __device__ __forceinline__ float xor_lane(float x) {
    if constexpr (D == 1)       return dppf<0xB1>(x);
    else if constexpr (D == 2)  return dppf<0x4E>(x);
    else if constexpr (D == 4)  return dppf<0x141>(dppf<0x4E>(dppf<0xB1>(x)));
    else if constexpr (D == 8)  return dppf<0x128>(x);
    else                        return __shfl_xor(x, D, 64);
}
template <int N> struct IC { static constexpr int value = N; };

// ---------------------------------------------------------------------------
// Fused prep kernel: zero_guard (blocks 0..1079) + convert_w (1080..1847)
// + convert_x (1848..2135). One dispatch instead of three (saves 2 graph-node
// gaps). Bodies identical to the previously verified standalone kernels.
// ---------------------------------------------------------------------------
#define ROW4  (RS * OC3 / 4)       // 10752 float4 per spatial row
#define REG1  (6 * ROW4)           // 6 full guard rows (0,1,2,51,52,53)
#define COLS4 (OC3 / 4)            // 192 float4 per cell

__global__ __launch_bounds__(256) void prep(
    float* __restrict__ Y2,
    const float* __restrict__ W, short* __restrict__ Wt,
    const float* __restrict__ X, short* __restrict__ Xt)
{
    __shared__ float tile[64][65];
    const int bid = blockIdx.x;
    const int t   = threadIdx.x;

    if (bid < 1080) {
        // ---- zero_guard: zero only the guard cells of Y2 ----
        const int idx = (bid % 540) * 256 + t;      // 0 .. 138239
        const int b   = bid / 540;
        float4* Yb = (float4*)(Y2 + (size_t)b * BSTRIDE);
        const float4 z = make_float4(0.f, 0.f, 0.f, 0.f);
        if (idx < REG1) {
            int r6  = idx / ROW4;
            int rem = idx - r6 * ROW4;
            int r   = (r6 < 3) ? r6 : 48 + r6;      // 0,1,2,51,52,53
            Yb[r * ROW4 + rem] = z;
        } else {
            int i2  = idx - REG1;
            int r   = 3 + i2 / (8 * COLS4);         // 3..50
            int rem = i2 - (r - 3) * (8 * COLS4);
            int cg  = rem / COLS4;
            int c   = (cg < 3) ? cg : 48 + cg;      // 0,1,2,51..55
            int ch4 = rem - cg * COLS4;
            Yb[(r * RS + c) * COLS4 + ch4] = z;
        }
    } else if (bid < 1848) {
        // ---- convert_w: W (768,256) fp32 -> Wt (768,512) bf16 hi|lo ----
        int tt = (bid - 1080) * 256 + t;            // 0 .. 196607
        int o = tt >> 8, c = tt & 255;
        float v = W[tt];
        unsigned short hi = f2bf_rne(v);
        unsigned short lo = f2bf_rne(v - bf2f(hi));
        Wt[(size_t)o * 512 + c]       = (short)hi;
        Wt[(size_t)o * 512 + 256 + c] = (short)lo;
    } else {
        // ---- convert_x: X (B,256,2304) fp32 -> Xt (B,2304,512) bf16 hi|lo
        const int blk = bid - 1848;                 // 0 .. 287
        const int p0  = (blk % 36) * 64;
        const int c0  = ((blk / 36) & 3) * 64;
        const int b   = blk / 144;

        const float* Xb = X + (size_t)b * CIN * PP;
        #pragma unroll
        for (int r = 0; r < 16; ++r) {
            int idx = r * 256 + t;
            int c = idx >> 6, p = idx & 63;
            tile[c][p] = Xb[(size_t)(c0 + c) * PP + p0 + p];
        }
        __syncthreads();
        short* Xo = Xt + (size_t)b * PP * 512;
        #pragma unroll
        for (int r = 0; r < 16; ++r) {
            int idx = r * 256 + t;
            int p = idx >> 6, c = idx & 63;
            float v = tile[c][p];
            unsigned short hi = f2bf_rne(v);
            unsigned short lo = f2bf_rne(v - bf2f(hi));
            size_t base = (size_t)(p0 + p) * 512 + c0 + c;
            Xo[base]       = (short)hi;
            Xo[base + 256] = (short)lo;
        }
    }
}

// ---------------------------------------------------------------------------
// Kernel 1: conv as split-bf16 MFMA GEMM, 3-term product (r5-verified):
//   k0 in [0,256):   W hi x X hi ; [256,512): W hi x X lo ; [512,768): W lo x X hi
// Tile 64(o) x 64(p), grid 36x12x2 = 864 blocks (3.4/CU). 4 waves per block,
// each a 32x32 quadrant (2x2 MFMA 16x16x32).  (unchanged)
// ---------------------------------------------------------------------------
#define LDA 40   // shorts per LDS row (32 + 8 pad)

__global__ __launch_bounds__(256, 4) void conv_mfma(
    const short* __restrict__ Wt,   // (768, 512)
    const short* __restrict__ Xt,   // (B, 2304, 512)
    float* __restrict__ Y2)
{
    __shared__ short As[64 * LDA];   // [o][k]
    __shared__ short Bs[64 * LDA];   // [p][k]

    const int tid = threadIdx.x;
    const int bn  = blockIdx.x;       // p tile (36)
    const int bm  = blockIdx.y;       // o tile (12)
    const int b   = blockIdx.z;
    const int om0 = bm * 64, pn0 = bn * 64;

    const int lane = tid & 63, w = tid >> 6;
    const int oq = (w & 1) * 32, pq = (w >> 1) * 32;
    const int ln15 = lane & 15, q = lane >> 4;

    const int  lrow  = (tid & 127) >> 1;    // 0..63
    const int  lsoff = (tid & 1) * 16;      // 0 or 16 shorts
    const bool isA   = tid < 128;
    const short* gA = Wt + (size_t)(om0 + lrow) * 512 + lsoff;
    const short* gB = Xt + (size_t)b * PP * 512 + (size_t)(pn0 + lrow) * 512 + lsoff;
    const short* gsrc = isA ? gA : gB;
    short* ldst = (isA ? As : Bs) + lrow * LDA + lsoff;

    f32x4 acc[2][2] = {};

    for (int k0 = 0; k0 < 768; k0 += 32) {
        const int wk = (k0 < 256) ? k0 : k0 - 256;   // W: hi, hi, lo
        const int xk = (k0 < 512) ? k0 : k0 - 512;   // X: hi, lo, hi
        const int kk = isA ? wk : xk;
        uint4 v0 = *(const uint4*)(gsrc + kk);
        uint4 v1 = *(const uint4*)(gsrc + kk + 8);
        __syncthreads();
        *(uint4*)ldst       = v0;
        *(uint4*)(ldst + 8) = v1;
        __syncthreads();

        bf16x8 af[2], bf[2];
        #pragma unroll
        for (int i = 0; i < 2; ++i) {
            af[i] = *(const bf16x8*)&As[(oq + i * 16 + ln15) * LDA + q * 8];
            bf[i] = *(const bf16x8*)&Bs[(pq + i * 16 + ln15) * LDA + q * 8];
        }
        #pragma unroll
        for (int i = 0; i < 2; ++i)
            #pragma unroll
            for (int j = 0; j < 2; ++j)
                acc[i][j] = __builtin_amdgcn_mfma_f32_16x16x32_bf16(
                    af[i], bf[j], acc[i][j], 0, 0, 0);
    }

    // D[m=o][n=p]: lane = col p (ln15), rows o = q*4..q*4+3 contiguous
    float* Yb = Y2 + (size_t)b * BSTRIDE + IOFF;
    #pragma unroll
    for (int i = 0; i < 2; ++i) {
        #pragma unroll
        for (int j = 0; j < 2; ++j) {
            int o = om0 + oq + i * 16 + q * 4;
            int p = pn0 + pq + j * 16 + ln15;
            int h = p / 48, ww = p - h * 48;
            *(f32x4*)&Yb[(size_t)(h * RS + ww) * OC3 + o] = acc[i][j];
        }
    }
}

// ---------------------------------------------------------------------------
// Kernel 2: attention. One wave per (b,g,p'). XCD-swizzled.
// r7: all xor-shuffles with d in {1,2,4,8} moved from the CU-shared LDS pipe
// (ds_swizzle/bpermute, ~30 cyc) to per-SIMD VALU DPP (~2 cyc), exact
// permutation semantics. Math unchanged.
// ---------------------------------------------------------------------------
struct TagH { static constexpr bool value = true;  };
struct TagW { static constexpr bool value = false; };

__global__ __launch_bounds__(256, 4) void attn_kernel(
    const float* __restrict__ Y2,
    const float* __restrict__ rpe_h,  // (4,1,7,1,32)
    const float* __restrict__ rpe_w,  // (4,1,1,7,32)
    float* __restrict__ out)          // (B, 256, 48, 48)
{
    __shared__ float xpose[4][65];

    const int tid  = threadIdx.x;
    const int lane = tid & 63;
    const int w    = tid >> 6;
    const int bx     = blockIdx.x;
    const int wblock = (bx & 7) * 576 + (bx >> 3);
    const int wid    = wblock * 4 + w;
    const int pq   = wid % PP;
    const int g    = (wid / PP) & (NG - 1);
    const int b    = wid / (PP * NG);
    const int ph   = pq / 48;
    const int pw   = pq - ph * 48;

    const float* Yb = Y2 + (size_t)b * BSTRIDE + IOFF;

    const float qv = Yb[(size_t)(ph * RS + pw) * OC3 + g * GOC + lane];

    const int t   = (pq >= HALF_P) ? 1 : 0;
    const int qpr = pq - t * HALF_P;
    const int p0  = 2 * qpr;
    const int ph0 = p0 / 48;
    const int pw0 = p0 - ph0 * 48;
    const int g2  = 2 * g + t;
    const bool use_h = (g2 < NG);
    const int  kch   = use_h ? (CIN + g2 * GOC) : (CIN + (g2 - NG) * GOC + C2);
    const float* rb  = use_h ? (rpe_h + g2 * 7 * C2) : (rpe_w + (g2 - NG) * 7 * C2);

    const int  c  = lane & 31;
    const bool hi = (lane >= 32);

    const float R0 = rb[0 * C2 + c], R1 = rb[1 * C2 + c], R2 = rb[2 * C2 + c],
                R3 = rb[3 * C2 + c], R4 = rb[4 * C2 + c], R5 = rb[5 * C2 + c],
                R6 = rb[6 * C2 + c];

    const float* kb = Yb + (size_t)(ph0 * RS + pw0) * OC3 + kch + c;

    auto rget = [&](int idx) -> float {
        return idx == 0 ? R0 : idx == 1 ? R1 : idx == 2 ? R2 :
               idx == 3 ? R3 : idx == 4 ? R4 : idx == 5 ? R5 : R6;
    };

    auto tree = [&](auto tag) -> float {
        constexpr bool UH = decltype(tag)::value;
        auto chunkprod = [&](int l) -> float {
            int m0 = 2 * l,     h10 = (m0 >= KK), k0 = m0 - KK * h10;
            int m1 = 2 * l + 1, h11 = (m1 >= KK), k1 = m1 - KK * h11;
            int i0 = k0 / 7, j0 = k0 % 7, i1 = k1 / 7, j1 = k1 % 7;
            int d0 = ((i0 - 3) * RS + (h10 + j0 - 3)) * OC3;
            int d1 = ((i1 - 3) * RS + (h11 + j1 - 3)) * OC3;
            float kv = kb[hi ? d1 : d0];
            float ra = UH ? rget(i0) : rget(j0);
            float rc = UH ? rget(i1) : rget(j1);
            kv += hi ? rc : ra;
            return qv * kv;
        };
        float sv[32];
        #pragma unroll
        for (int jj = 0; jj < 32; ++jj) {
            if (2 * jj >= KK) { sv[jj] = 0.f; continue; }
            float pa = chunkprod(2 * jj);
            float pb = (2 * jj + 1 < KK) ? chunkprod(2 * jj + 1) : 0.f;
            float u  = (lane & 1) ? pb : pa;
            float ww = (lane & 1) ? pa : pb;
            sv[jj] = u + xor_lane<1>(ww);
        }
        auto level = [&](auto dc) {
            constexpr int d = decltype(dc)::value;
            #pragma unroll
            for (int i = 0; i < 32; i += d) {
                float a  = sv[i], bb = sv[i + d / 2];
                float u  = (lane & d) ? bb : a;
                float ww = (lane & d) ? a : bb;
                sv[i] = u + xor_lane<d>(ww);
            }
        };
        level(IC<2>{});
        level(IC<4>{});
        level(IC<8>{});
        level(IC<16>{});
        level(IC<32>{});
        return sv[0];
    };

    const float logit = use_h ? tree(TagH{}) : tree(TagW{});

    float mx = logit;
    mx = fmaxf(mx, xor_lane<1>(mx));
    mx = fmaxf(mx, xor_lane<2>(mx));
    mx = fmaxf(mx, xor_lane<4>(mx));
    mx = fmaxf(mx, xor_lane<8>(mx));
    mx = fmaxf(mx, xor_lane<16>(mx));
    mx = fmaxf(mx, xor_lane<32>(mx));
    float e = (lane < KK) ? __expf(logit - mx) : 0.f;
    float ssum = e;
    ssum += xor_lane<1>(ssum);
    ssum += xor_lane<2>(ssum);
    ssum += xor_lane<4>(ssum);
    ssum += xor_lane<8>(ssum);
    ssum += xor_lane<16>(ssum);
    ssum += xor_lane<32>(ssum);
    const float att = e / ssum;

    float acc = 0.f;
    const float* vb = Yb + (size_t)(ph * RS + pw) * OC3 + 2 * CIN + g * GOC + lane;
    #pragma unroll
    for (int k = 0; k < KK; ++k) {
        int i = k / 7, j = k % 7;
        int doff = ((i - 3) * RS + (j - 3)) * OC3;
        float ak = __uint_as_float(
            __builtin_amdgcn_readlane(__float_as_uint(att), k));
        acc = fmaf(ak, vb[doff], acc);
    }

    xpose[w][lane] = acc;
    __syncthreads();
    const int wid0 = wblock * 4;
    const int pq0  = wid0 % PP;
    const int g0   = (wid0 / PP) & (NG - 1);
    const int b0   = wid0 / (PP * NG);
    const int ch   = tid >> 2;
    const int w2   = tid & 3;
    out[((size_t)b0 * 256 + g0 * GOC + ch) * PP + pq0 + w2] = xpose[w2][ch];
}

// ---------------------------------------------------------------------------
extern "C" void kernel_launch(void* const* d_in, const int* in_sizes, int n_in,
                              void* d_out, int out_size, void* d_ws, size_t ws_size,
                              hipStream_t stream)
{
    const float* x  = (const float*)d_in[0];
    const float* w  = (const float*)d_in[1];
    const float* rh = (const float*)d_in[2];
    const float* rw = (const float*)d_in[3];

    float* Y2 = (float*)d_ws;
    short* Xt = (short*)((char*)d_ws + XT_OFF);
    short* Wt = (short*)((char*)d_ws + WT_OFF);

    prep<<<2136, 256, 0, stream>>>(Y2, w, Wt, x, Xt);
    conv_mfma<<<dim3(36, 12, BB), 256, 0, stream>>>(Wt, Xt, Y2);
    attn_kernel<<<(BB * NG * PP) / 4, 256, 0, stream>>>(Y2, rh, rw, (float*)d_out);
}

// Round 2
// 112.306 us; speedup vs baseline: 1.0483x; 1.0008x over previous
//
#include <hip/hip_runtime.h>

// Problem constants
#define BB   2
#define CIN  256
#define OC3  768
#define NG   4
#define GOC  64
#define C2   32
#define KK   49
#define PP   2304
#define HALF_P 1152

// Guarded Y2 layout: rows -3..50 (54), cols -3..52 at stride 56, 768 ch.
#define RS      56
#define BROWS   54
#define BSTRIDE (BROWS * RS * OC3)          // floats per batch = 2,322,432
#define IOFF    ((3 * RS + 3) * OC3)

// Workspace layout (bytes)
#define Y2_BYTES  (BB * BROWS * RS * OC3 * 4)
#define XT_OFF    Y2_BYTES
#define WT_OFF    (XT_OFF + BB * PP * 512 * 2)

typedef __attribute__((ext_vector_type(8))) short bf16x8;
typedef __attribute__((ext_vector_type(4))) float f32x4;

static __device__ __forceinline__ unsigned short f2bf_rne(float x) {
    unsigned int u = __float_as_uint(x);
    unsigned int r = u + 0x7FFFu + ((u >> 16) & 1u);
    return (unsigned short)(r >> 16);
}
static __device__ __forceinline__ float bf2f(unsigned short h) {
    return __uint_as_float(((unsigned int)h) << 16);
}

// ---------------------------------------------------------------------------
// DPP-based exact xor-lane exchange (VALU pipe). Bit-identical semantics.
//   xor1 = quad_perm{1,0,3,2} = 0xB1
//   xor2 = quad_perm{2,3,0,1} = 0x4E
//   xor8 = row_ror:8 (0x128)
//   xor4 = xor1 ∘ xor2 ∘ xor7(row_half_mirror 0x141), since 1^2^7 = 4
//   xor16/xor32 stay on the LDS path (no single gfx9 DPP ctrl).
// ---------------------------------------------------------------------------
template <int C>
static __device__ __forceinline__ float dppf(float x) {
    return __int_as_float(__builtin_amdgcn_update_dpp(
        0, __float_as_int(x), C, 0xF, 0xF, true));
}
template <int D>
static __device__ __forceinline__ float xor_lane(float x) {
    if constexpr (D == 1)       return dppf<0xB1>(x);
    else if constexpr (D == 2)  return dppf<0x4E>(x);
    else if constexpr (D == 4)  return dppf<0x141>(dppf<0x4E>(dppf<0xB1>(x)));
    else if constexpr (D == 8)  return dppf<0x128>(x);
    else                        return __shfl_xor(x, D, 64);
}
template <int N> struct IC { static constexpr int value = N; };

// ---------------------------------------------------------------------------
// Fused prep kernel: zero_guard (blocks 0..1079) + convert_w (1080..1847)
// + convert_x (1848..2135).  (unchanged from r7)
// ---------------------------------------------------------------------------
#define ROW4  (RS * OC3 / 4)       // 10752 float4 per spatial row
#define REG1  (6 * ROW4)           // 6 full guard rows (0,1,2,51,52,53)
#define COLS4 (OC3 / 4)            // 192 float4 per cell

__global__ __launch_bounds__(256) void prep(
    float* __restrict__ Y2,
    const float* __restrict__ W, short* __restrict__ Wt,
    const float* __restrict__ X, short* __restrict__ Xt)
{
    __shared__ float tile[64][65];
    const int bid = blockIdx.x;
    const int t   = threadIdx.x;

    if (bid < 1080) {
        const int idx = (bid % 540) * 256 + t;      // 0 .. 138239
        const int b   = bid / 540;
        float4* Yb = (float4*)(Y2 + (size_t)b * BSTRIDE);
        const float4 z = make_float4(0.f, 0.f, 0.f, 0.f);
        if (idx < REG1) {
            int r6  = idx / ROW4;
            int rem = idx - r6 * ROW4;
            int r   = (r6 < 3) ? r6 : 48 + r6;      // 0,1,2,51,52,53
            Yb[r * ROW4 + rem] = z;
        } else {
            int i2  = idx - REG1;
            int r   = 3 + i2 / (8 * COLS4);         // 3..50
            int rem = i2 - (r - 3) * (8 * COLS4);
            int cg  = rem / COLS4;
            int c   = (cg < 3) ? cg : 48 + cg;      // 0,1,2,51..55
            int ch4 = rem - cg * COLS4;
            Yb[(r * RS + c) * COLS4 + ch4] = z;
        }
    } else if (bid < 1848) {
        int tt = (bid - 1080) * 256 + t;            // 0 .. 196607
        int o = tt >> 8, c = tt & 255;
        float v = W[tt];
        unsigned short hi = f2bf_rne(v);
        unsigned short lo = f2bf_rne(v - bf2f(hi));
        Wt[(size_t)o * 512 + c]       = (short)hi;
        Wt[(size_t)o * 512 + 256 + c] = (short)lo;
    } else {
        const int blk = bid - 1848;                 // 0 .. 287
        const int p0  = (blk % 36) * 64;
        const int c0  = ((blk / 36) & 3) * 64;
        const int b   = blk / 144;

        const float* Xb = X + (size_t)b * CIN * PP;
        #pragma unroll
        for (int r = 0; r < 16; ++r) {
            int idx = r * 256 + t;
            int c = idx >> 6, p = idx & 63;
            tile[c][p] = Xb[(size_t)(c0 + c) * PP + p0 + p];
        }
        __syncthreads();
        short* Xo = Xt + (size_t)b * PP * 512;
        #pragma unroll
        for (int r = 0; r < 16; ++r) {
            int idx = r * 256 + t;
            int p = idx >> 6, c = idx & 63;
            float v = tile[c][p];
            unsigned short hi = f2bf_rne(v);
            unsigned short lo = f2bf_rne(v - bf2f(hi));
            size_t base = (size_t)(p0 + p) * 512 + c0 + c;
            Xo[base]       = (short)hi;
            Xo[base + 256] = (short)lo;
        }
    }
}

// ---------------------------------------------------------------------------
// Kernel 1: conv as split-bf16 MFMA GEMM (unchanged).
// ---------------------------------------------------------------------------
#define LDA 40   // shorts per LDS row (32 + 8 pad)

__global__ __launch_bounds__(256, 4) void conv_mfma(
    const short* __restrict__ Wt,   // (768, 512)
    const short* __restrict__ Xt,   // (B, 2304, 512)
    float* __restrict__ Y2)
{
    __shared__ short As[64 * LDA];   // [o][k]
    __shared__ short Bs[64 * LDA];   // [p][k]

    const int tid = threadIdx.x;
    const int bn  = blockIdx.x;       // p tile (36)
    const int bm  = blockIdx.y;       // o tile (12)
    const int b   = blockIdx.z;
    const int om0 = bm * 64, pn0 = bn * 64;

    const int lane = tid & 63, w = tid >> 6;
    const int oq = (w & 1) * 32, pq = (w >> 1) * 32;
    const int ln15 = lane & 15, q = lane >> 4;

    const int  lrow  = (tid & 127) >> 1;    // 0..63
    const int  lsoff = (tid & 1) * 16;      // 0 or 16 shorts
    const bool isA   = tid < 128;
    const short* gA = Wt + (size_t)(om0 + lrow) * 512 + lsoff;
    const short* gB = Xt + (size_t)b * PP * 512 + (size_t)(pn0 + lrow) * 512 + lsoff;
    const short* gsrc = isA ? gA : gB;
    short* ldst = (isA ? As : Bs) + lrow * LDA + lsoff;

    f32x4 acc[2][2] = {};

    for (int k0 = 0; k0 < 768; k0 += 32) {
        const int wk = (k0 < 256) ? k0 : k0 - 256;   // W: hi, hi, lo
        const int xk = (k0 < 512) ? k0 : k0 - 512;   // X: hi, lo, hi
        const int kk = isA ? wk : xk;
        uint4 v0 = *(const uint4*)(gsrc + kk);
        uint4 v1 = *(const uint4*)(gsrc + kk + 8);
        __syncthreads();
        *(uint4*)ldst       = v0;
        *(uint4*)(ldst + 8) = v1;
        __syncthreads();

        bf16x8 af[2], bf[2];
        #pragma unroll
        for (int i = 0; i < 2; ++i) {
            af[i] = *(const bf16x8*)&As[(oq + i * 16 + ln15) * LDA + q * 8];
            bf[i] = *(const bf16x8*)&Bs[(pq + i * 16 + ln15) * LDA + q * 8];
        }
        #pragma unroll
        for (int i = 0; i < 2; ++i)
            #pragma unroll
            for (int j = 0; j < 2; ++j)
                acc[i][j] = __builtin_amdgcn_mfma_f32_16x16x32_bf16(
                    af[i], bf[j], acc[i][j], 0, 0, 0);
    }

    // D[m=o][n=p]: lane = col p (ln15), rows o = q*4..q*4+3 contiguous
    float* Yb = Y2 + (size_t)b * BSTRIDE + IOFF;
    #pragma unroll
    for (int i = 0; i < 2; ++i) {
        #pragma unroll
        for (int j = 0; j < 2; ++j) {
            int o = om0 + oq + i * 16 + q * 4;
            int p = pn0 + pq + j * 16 + ln15;
            int h = p / 48, ww = p - h * 48;
            *(f32x4*)&Yb[(size_t)(h * RS + ww) * OC3 + o] = acc[i][j];
        }
    }
}

// ---------------------------------------------------------------------------
// Kernel 2: attention. One wave per (b,g,p'). XCD-swizzled.
// r8: streaming binary-tree reduction (live set ~10 floats instead of sv[32],
// identical pairing/ops as the old level() loops -> bit-identical numerics)
// frees ~25 VGPRs; occupancy raised to 6 blocks/CU (6 waves/SIMD) to hide
// scattered-VMEM latency.
// ---------------------------------------------------------------------------
struct TagH { static constexpr bool value = true;  };
struct TagW { static constexpr bool value = false; };

__global__ __launch_bounds__(256, 6) void attn_kernel(
    const float* __restrict__ Y2,
    const float* __restrict__ rpe_h,  // (4,1,7,1,32)
    const float* __restrict__ rpe_w,  // (4,1,1,7,32)
    float* __restrict__ out)          // (B, 256, 48, 48)
{
    __shared__ float xpose[4][65];

    const int tid  = threadIdx.x;
    const int lane = tid & 63;
    const int w    = tid >> 6;
    const int bx     = blockIdx.x;
    const int wblock = (bx & 7) * 576 + (bx >> 3);
    const int wid    = wblock * 4 + w;
    const int pq   = wid % PP;
    const int g    = (wid / PP) & (NG - 1);
    const int b    = wid / (PP * NG);
    const int ph   = pq / 48;
    const int pw   = pq - ph * 48;

    const float* Yb = Y2 + (size_t)b * BSTRIDE + IOFF;

    const float qv = Yb[(size_t)(ph * RS + pw) * OC3 + g * GOC + lane];

    const int t   = (pq >= HALF_P) ? 1 : 0;
    const int qpr = pq - t * HALF_P;
    const int p0  = 2 * qpr;
    const int ph0 = p0 / 48;
    const int pw0 = p0 - ph0 * 48;
    const int g2  = 2 * g + t;
    const bool use_h = (g2 < NG);
    const int  kch   = use_h ? (CIN + g2 * GOC) : (CIN + (g2 - NG) * GOC + C2);
    const float* rb  = use_h ? (rpe_h + g2 * 7 * C2) : (rpe_w + (g2 - NG) * 7 * C2);

    const int  c  = lane & 31;
    const bool hi = (lane >= 32);

    const float R0 = rb[0 * C2 + c], R1 = rb[1 * C2 + c], R2 = rb[2 * C2 + c],
                R3 = rb[3 * C2 + c], R4 = rb[4 * C2 + c], R5 = rb[5 * C2 + c],
                R6 = rb[6 * C2 + c];

    const float* kb = Yb + (size_t)(ph0 * RS + pw0) * OC3 + kch + c;

    auto rget = [&](int idx) -> float {
        return idx == 0 ? R0 : idx == 1 ? R1 : idx == 2 ? R2 :
               idx == 3 ? R3 : idx == 4 ? R4 : idx == 5 ? R5 : R6;
    };

    auto tree = [&](auto tag) -> float {
        constexpr bool UH = decltype(tag)::value;
        auto chunkprod = [&](int l) -> float {
            int m0 = 2 * l,     h10 = (m0 >= KK), k0 = m0 - KK * h10;
            int m1 = 2 * l + 1, h11 = (m1 >= KK), k1 = m1 - KK * h11;
            int i0 = k0 / 7, j0 = k0 % 7, i1 = k1 / 7, j1 = k1 % 7;
            int d0 = ((i0 - 3) * RS + (h10 + j0 - 3)) * OC3;
            int d1 = ((i1 - 3) * RS + (h11 + j1 - 3)) * OC3;
            float kv = kb[hi ? d1 : d0];
            float ra = UH ? rget(i0) : rget(j0);
            float rc = UH ? rget(i1) : rget(j1);
            kv += hi ? rc : ra;
            return qv * kv;
        };
        // value at tree leaf jj (includes the d=1 exchange) -- identical to
        // the old sv[jj] computation.
        auto val = [&](int jj) -> float {
            if (2 * jj >= KK) return 0.f;
            float pa = chunkprod(2 * jj);
            float pb = (2 * jj + 1 < KK) ? chunkprod(2 * jj + 1) : 0.f;
            float u  = (lane & 1) ? pb : pa;
            float ww = (lane & 1) ? pa : pb;
            return u + xor_lane<1>(ww);
        };
        auto comb = [&](auto dc, float x, float y) -> float {
            constexpr int d = decltype(dc)::value;
            float u  = (lane & d) ? y : x;
            float ww = (lane & d) ? x : y;
            return u + xor_lane<d>(ww);
        };
        // Streaming binary tree: same pairing as the old level() loops
        // (jj-pairs at d=2, quads at d=4, ...) but with ~10 live floats
        // instead of a 32-register sv[] array.
        float acc32[2];
        #pragma unroll
        for (int a = 0; a < 2; ++a) {
            float acc16[2];
            #pragma unroll
            for (int bq = 0; bq < 2; ++bq) {
                float acc8[2];
                #pragma unroll
                for (int cq = 0; cq < 2; ++cq) {
                    float acc4[2];
                    #pragma unroll
                    for (int dq = 0; dq < 2; ++dq) {
                        float acc2[2];
                        #pragma unroll
                        for (int eq = 0; eq < 2; ++eq)
                            acc2[eq] = val(a * 16 + bq * 8 + cq * 4 + dq * 2 + eq);
                        acc4[dq] = comb(IC<2>{}, acc2[0], acc2[1]);
                    }
                    acc8[cq] = comb(IC<4>{}, acc4[0], acc4[1]);
                }
                acc16[bq] = comb(IC<8>{}, acc8[0], acc8[1]);
            }
            acc32[a] = comb(IC<16>{}, acc16[0], acc16[1]);
        }
        return comb(IC<32>{}, acc32[0], acc32[1]);
    };

    const float logit = use_h ? tree(TagH{}) : tree(TagW{});

    float mx = logit;
    mx = fmaxf(mx, xor_lane<1>(mx));
    mx = fmaxf(mx, xor_lane<2>(mx));
    mx = fmaxf(mx, xor_lane<4>(mx));
    mx = fmaxf(mx, xor_lane<8>(mx));
    mx = fmaxf(mx, xor_lane<16>(mx));
    mx = fmaxf(mx, xor_lane<32>(mx));
    float e = (lane < KK) ? __expf(logit - mx) : 0.f;
    float ssum = e;
    ssum += xor_lane<1>(ssum);
    ssum += xor_lane<2>(ssum);
    ssum += xor_lane<4>(ssum);
    ssum += xor_lane<8>(ssum);
    ssum += xor_lane<16>(ssum);
    ssum += xor_lane<32>(ssum);
    const float att = e / ssum;

    float acc = 0.f;
    const float* vb = Yb + (size_t)(ph * RS + pw) * OC3 + 2 * CIN + g * GOC + lane;
    #pragma unroll
    for (int k = 0; k < KK; ++k) {
        int i = k / 7, j = k % 7;
        int doff = ((i - 3) * RS + (j - 3)) * OC3;
        float ak = __uint_as_float(
            __builtin_amdgcn_readlane(__float_as_uint(att), k));
        acc = fmaf(ak, vb[doff], acc);
    }

    xpose[w][lane] = acc;
    __syncthreads();
    const int wid0 = wblock * 4;
    const int pq0  = wid0 % PP;
    const int g0   = (wid0 / PP) & (NG - 1);
    const int b0   = wid0 / (PP * NG);
    const int ch   = tid >> 2;
    const int w2   = tid & 3;
    out[((size_t)b0 * 256 + g0 * GOC + ch) * PP + pq0 + w2] = xpose[w2][ch];
}

// ---------------------------------------------------------------------------
extern "C" void kernel_launch(void* const* d_in, const int* in_sizes, int n_in,
                              void* d_out, int out_size, void* d_ws, size_t ws_size,
                              hipStream_t stream)
{
    const float* x  = (const float*)d_in[0];
    const float* w  = (const float*)d_in[1];
    const float* rh = (const float*)d_in[2];
    const float* rw = (const float*)d_in[3];

    float* Y2 = (float*)d_ws;
    short* Xt = (short*)((char*)d_ws + XT_OFF);
    short* Wt = (short*)((char*)d_ws + WT_OFF);

    prep<<<2136, 256, 0, stream>>>(Y2, w, Wt, x, Xt);
    conv_mfma<<<dim3(36, 12, BB), 256, 0, stream>>>(Wt, Xt, Y2);
    attn_kernel<<<(BB * NG * PP) / 4, 256, 0, stream>>>(Y2, rh, rw, (float*)d_out);
}